// Round 4
// baseline (194.123 us; speedup 1.0000x reference)
//
#include <hip/hip_runtime.h>

// x[1,32,14,14,14] -> trilinear upsample(224, align_corners) -> 1x1x1 conv
// (32->4) -> softmax(dim=1). Output [1,4,224,224,224] fp32.
//
// Conv commutes with (linear) interpolation -> contract 32->4 first.
// Structure (identical to R2): one block per output d-plane (grid=224):
//   phase 0: conv on the 2 source d-planes this block needs
//   phase 1: d-lerp -> e[14][14]   (log2(e) folded in; interp is affine)
//   phase 2: h-lerp -> g[224][15] in LDS
//   phase 3: w-lerp + softmax + coalesced float4 stores
//
// R4 = R3 with the compile fix: __builtin_nontemporal_store requires a
// native vector type, not HIP_vector_type. Use ext_vector_type(4) float.
// Hypothesis under test: L2 write-allocate churn caps the store stream at
// ~2.5 TB/s (fill does 6.6 TB/s); `nt` marks lines no-allocate/evict-first.

#define NSP 2744             // 14^3
#define NPLANE 196           // 14*14
#define NV  11239424u        // 224^3
#define PLANE_OUT 50176u     // 224*224
#define RATIO (13.0f / 223.0f)
#define LOG2E 1.44269504088896340736f

typedef float nfloat4 __attribute__((ext_vector_type(4)));

__global__ __launch_bounds__(1024) void fused_decoder(
    const float* __restrict__ x,   // [32][2744]
    const float* __restrict__ W,   // [4][32]
    const float* __restrict__ b,   // [4]
    float* __restrict__ out)       // [4][224][224][224]
{
    __shared__ float4 zloc[2 * NPLANE];   //  6,272 B: conv output, 2 d-planes
    __shared__ float4 etab[NPLANE];       //  3,136 B: d-lerped, log2e-scaled
    __shared__ float4 gtab[224 * 15];     // 53,760 B: h-lerped lines (pad 14->15)

    const int   t    = threadIdx.x;
    const unsigned dd = blockIdx.x;            // output d-plane, uniform
    const float posd = (float)dd * RATIO;
    const int   i0d  = min((int)posd, 12);
    const float wd   = posd - (float)i0d;

    // ---- phase 0: 32->4 conv on the two source d-planes ----
    if (t < 2 * NPLANE) {
        int pl   = t / NPLANE;                 // 0 or 1
        int s    = t - pl * NPLANE;
        int base = (i0d + pl) * NPLANE + s;
        float a0 = b[0], a1 = b[1], a2 = b[2], a3 = b[3];
#pragma unroll
        for (int c = 0; c < 32; ++c) {
            float xv = x[c * NSP + base];
            a0 = fmaf(W[c],      xv, a0);
            a1 = fmaf(W[32 + c], xv, a1);
            a2 = fmaf(W[64 + c], xv, a2);
            a3 = fmaf(W[96 + c], xv, a3);
        }
        zloc[t] = make_float4(a0, a1, a2, a3);
    }
    __syncthreads();

    // ---- phase 1: d-lerp + fold log2(e) ----
    if (t < NPLANE) {
        float4 z0 = zloc[t], z1 = zloc[NPLANE + t];
        float4 ev;
        ev.x = fmaf(wd, z1.x - z0.x, z0.x) * LOG2E;
        ev.y = fmaf(wd, z1.y - z0.y, z0.y) * LOG2E;
        ev.z = fmaf(wd, z1.z - z0.z, z0.z) * LOG2E;
        ev.w = fmaf(wd, z1.w - z0.w, z0.w) * LOG2E;
        etab[t] = ev;
    }
    __syncthreads();

    // ---- phase 2: h-lerp -> gtab[h][iw] ----
    for (int k = t; k < 224 * 14; k += 1024) {
        int h  = k / 14;
        int iw = k - h * 14;
        float posh = (float)h * RATIO;
        int   i0h  = min((int)posh, 12);
        float wh   = posh - (float)i0h;
        float4 e0 = etab[i0h * 14 + iw];
        float4 e1 = etab[i0h * 14 + 14 + iw];
        float4 gv;
        gv.x = fmaf(wh, e1.x - e0.x, e0.x);
        gv.y = fmaf(wh, e1.y - e0.y, e0.y);
        gv.z = fmaf(wh, e1.z - e0.z, e0.z);
        gv.w = fmaf(wh, e1.w - e0.w, e0.w);
        gtab[h * 15 + iw] = gv;
    }
    __syncthreads();

    // ---- phase 3: w-lerp + softmax + NT stores ----
    const unsigned planeBase = dd * PLANE_OUT;
    for (int g4 = t; g4 < 12544; g4 += 1024) {   // 12544 = 224*56
        int w4 = g4 % 56;
        int h  = g4 / 56;
        int wb = w4 * 4;
        float posw0 = (float)wb * RATIO;
        int   iw0   = min((int)posw0, 12);
        float u     = posw0 - (float)iw0;
        int   gb    = h * 15 + iw0;
        int   iw2   = min(iw0 + 2, 13);
        float4 g0 = gtab[gb];
        float4 g1 = gtab[gb + 1];
        float4 g2 = gtab[h * 15 + iw2];

        float4 d10, d21;
        d10.x = g1.x - g0.x; d10.y = g1.y - g0.y; d10.z = g1.z - g0.z; d10.w = g1.w - g0.w;
        d21.x = g2.x - g1.x; d21.y = g2.y - g1.y; d21.z = g2.z - g1.z; d21.w = g2.w - g1.w;

        float4 res[4];
#pragma unroll
        for (int j = 0; j < 4; ++j) {
            // piecewise-linear in u: val = g0 + min(u,1)*d10 + max(u-1,0)*d21
            float a  = fminf(u, 1.0f);
            float bb = u - a;
            float t0 = fmaf(bb, d21.x, fmaf(a, d10.x, g0.x));
            float t1 = fmaf(bb, d21.y, fmaf(a, d10.y, g0.y));
            float t2 = fmaf(bb, d21.z, fmaf(a, d10.z, g0.z));
            float t3 = fmaf(bb, d21.w, fmaf(a, d10.w, g0.w));
            float m  = fmaxf(fmaxf(t0, t1), fmaxf(t2, t3));
            float e0 = exp2f(t0 - m), e1 = exp2f(t1 - m);
            float e2 = exp2f(t2 - m), e3 = exp2f(t3 - m);
            float s  = (e0 + e1) + (e2 + e3);
            float inv = __builtin_amdgcn_rcpf(s);
            res[j].x = e0 * inv;
            res[j].y = e1 * inv;
            res[j].z = e2 * inv;
            res[j].w = e3 * inv;
            u += RATIO;
        }

        // transpose to per-channel vectors, then non-temporal coalesced stores
        unsigned sidx = planeBase + (unsigned)h * 224u + (unsigned)wb;
        nfloat4 o0 = { res[0].x, res[1].x, res[2].x, res[3].x };
        nfloat4 o1 = { res[0].y, res[1].y, res[2].y, res[3].y };
        nfloat4 o2 = { res[0].z, res[1].z, res[2].z, res[3].z };
        nfloat4 o3 = { res[0].w, res[1].w, res[2].w, res[3].w };
        __builtin_nontemporal_store(o0, (nfloat4*)(out + 0u * NV + sidx));
        __builtin_nontemporal_store(o1, (nfloat4*)(out + 1u * NV + sidx));
        __builtin_nontemporal_store(o2, (nfloat4*)(out + 2u * NV + sidx));
        __builtin_nontemporal_store(o3, (nfloat4*)(out + 3u * NV + sidx));
    }
}

extern "C" void kernel_launch(void* const* d_in, const int* in_sizes, int n_in,
                              void* d_out, int out_size, void* d_ws, size_t ws_size,
                              hipStream_t stream) {
    const float* x = (const float*)d_in[0];   // [1,32,14,14,14]
    const float* W = (const float*)d_in[1];   // [4,32]
    const float* b = (const float*)d_in[2];   // [4]
    float* out = (float*)d_out;               // [1,4,224,224,224]
    (void)d_ws; (void)ws_size;

    fused_decoder<<<224, 1024, 0, stream>>>(x, W, b, out);
}